// Round 15
// baseline (269.033 us; speedup 1.0000x reference)
//
#include <hip/hip_runtime.h>
#include <hip/hip_fp16.h>

typedef _Float16 f16x8 __attribute__((ext_vector_type(8)));
typedef float f32x4 __attribute__((ext_vector_type(4)));

// B=64, T=2000, E=512, D=1024, CC=32, K=31, H=128, PAD=15

__device__ __forceinline__ unsigned short f2h(float f) {
  __half h = __float2half(f);   // v_cvt_f16_f32, RNE
  return __builtin_bit_cast(unsigned short, h);
}

__device__ __forceinline__ f16x8 u4_to_f16x8(uint4 v) {
  return __builtin_bit_cast(f16x8, v);
}

__device__ __forceinline__ f16x8 cvt8(float4 u, float4 v) {
  uint4 w;
  w.x = ((unsigned)f2h(u.y) << 16) | f2h(u.x);
  w.y = ((unsigned)f2h(u.w) << 16) | f2h(u.z);
  w.z = ((unsigned)f2h(v.y) << 16) | f2h(v.x);
  w.w = ((unsigned)f2h(v.w) << 16) | f2h(v.z);
  return u4_to_f16x8(w);
}

__device__ __forceinline__ float fast_tanh(float x) {
  return 1.f - 2.f / (__expf(2.f * x) + 1.f);
}

// ---------------- misc prep: decb (fp32), MTg, WTpack (unchanged r11) ----------------
__global__ __launch_bounds__(256) void prep_kernel(
    const float* __restrict__ dec_state, const float* __restrict__ W_dec,
    const float* __restrict__ b_enc, const float* __restrict__ conv_w,
    const float* __restrict__ W_att, const float* __restrict__ W_enc,
    float* __restrict__ decb, unsigned short* __restrict__ MTg,
    unsigned short* __restrict__ WTpack)
{
  const int blk = blockIdx.x, tid = threadIdx.x;
  if (blk < 32) {
    __shared__ float sd[2048];
    const int sub = tid >> 7, h = tid & 127;
    const int b = blk*2 + sub;
    for (int i = h; i < 1024; i += 128) sd[sub*1024 + i] = dec_state[b*1024 + i];
    __syncthreads();
    float acc = b_enc[h];
    #pragma unroll 8
    for (int d = 0; d < 1024; ++d) acc = fmaf(sd[sub*1024 + d], W_dec[d*128 + h], acc);
    decb[b*128 + h] = acc;
  } else if (blk < 96) {
    const int e0 = (blk - 32) * 8;
    #pragma unroll
    for (int jj = 0; jj < 4; ++jj) {
      int idx = tid + jj*256;
      int el = idx >> 7, hh = idx & 127;
      int e = e0 + el;
      int kc = e >> 6, ks = (e >> 5) & 1, lg = (e >> 3) & 3, j = e & 7;
      int nt = hh >> 4, lr = hh & 15;
      int dst = (((kc*2 + ks)*8 + nt)*64 + lg*16 + lr)*8 + j;
      WTpack[dst] = f2h(W_enc[e*128 + hh]);
    }
  } else {
    if (tid < 128) {
      const int h = tid;
      for (int k = 0; k < 31; ++k) {
        float a = 0.f;
        #pragma unroll
        for (int c = 0; c < 32; ++c) a = fmaf(conv_w[c*31 + k], W_att[c*128 + h], a);
        MTg[h*32 + k] = f2h(a);
      }
      MTg[h*32 + 31] = 0;
    }
  }
}

// ---------------- pack: enc (row-linear full-BW read) -> PK f16 fragment-major ----------------
// PK[frag(b,bx,w)][kc][ks][lane][j], frag stride 16KB: value = f2h(enc[b][min(t,1999)][e]),
// t = bx*256 + w*16 + lr, e = kc*64 + ks*32 + lg*8 + j, lane = lg*16 + lr.
__global__ __launch_bounds__(256) void pack_kernel(
    const float* __restrict__ enc, unsigned short* __restrict__ PK)
{
  const int b  = blockIdx.y;
  const int t0c = blockIdx.x * 256;
  const int tid = threadIdx.x;
  const int e4 = (tid & 127) * 4;
  const int kc = e4 >> 6, ks = (e4 >> 5) & 1, lg = (e4 >> 3) & 3, jh = e4 & 7;
  const float* encB = enc + (size_t)b * (2000u*512u);
  char* pkB = (char*)PK + (size_t)(b*8 + blockIdx.x)*16*16384;
  #pragma unroll 4
  for (int c = 0; c < 32; ++c) {
    int row = 2*c + (tid >> 7);                 // local row 0..63 per quarter... (2 rows/iter)
    // iterate 4 quarters of 256 rows: c covers 0..31 with row = 2c+half -> 64 rows; loop quarters:
    #pragma unroll
    for (int q = 0; q < 4; ++q) {
      int lrow = q*64 + row;                    // 0..255
      int t = t0c + lrow;
      int src = t > 1999 ? 1999 : t;
      float4 v = *reinterpret_cast<const float4*>(encB + (size_t)src*512 + e4);
      uint2 wv;
      wv.x = ((unsigned)f2h(v.y) << 16) | f2h(v.x);
      wv.y = ((unsigned)f2h(v.w) << 16) | f2h(v.z);
      int w = lrow >> 4, lr = lrow & 15;
      char* dst = pkB + (size_t)w*16384 + kc*2048 + ks*1024 + (lg*16 + lr)*16 + jh*2;
      *reinterpret_cast<uint2*>(dst) = wv;
    }
  }
}

// ---------------- energy (PK): linear f16 A-stream + LDS-resident B, barrier-free ----------------
__global__ __launch_bounds__(1024, 4) void energy_pk_kernel(
    const unsigned short* __restrict__ PK, const float* __restrict__ prev,
    const unsigned short* __restrict__ WTpack, const unsigned short* __restrict__ MTg,
    const float* __restrict__ decb, const float* __restrict__ W_out,
    float* __restrict__ energy)
{
  extern __shared__ __align__(16) char smem[];
  unsigned short* sWT = (unsigned short*)smem;              // 131072 B
  unsigned short* sMT = (unsigned short*)(smem + 131072);   // 8192 B
  float* sPrev = (float*)(smem + 139264);
  float* sDecb = (float*)(smem + 140416);
  float* sWout = (float*)(smem + 140928);

  const int b  = blockIdx.y;
  const int t0 = blockIdx.x * 256;
  const int tid = threadIdx.x;
  const int wave = tid >> 6, lane = tid & 63;
  const int lr = lane & 15, lg = lane >> 4;

  {
    const uint4* wsrc = (const uint4*)WTpack;
    uint4* wdst = (uint4*)sWT;
    #pragma unroll
    for (int i = 0; i < 8; ++i) wdst[tid + i*1024] = wsrc[tid + i*1024];
    if (tid < 512) ((uint4*)sMT)[tid] = ((const uint4*)MTg)[tid];
    if (tid < 288) {
      int tt = t0 + tid - 15;
      sPrev[tid] = (tt >= 0 && tt < 2000) ? prev[b*2000 + tt] : 0.f;
    }
    if (tid < 128) { sDecb[tid] = decb[b*128 + tid]; sWout[tid] = W_out[tid]; }
  }
  __syncthreads();

  const char* apk = (const char*)PK + (size_t)((b*8 + blockIdx.x)*16 + wave)*16384 + lane*16;
  const char* wlds = (const char*)sWT + lane*16;

  f32x4 acc[8];
  #pragma unroll
  for (int i = 0; i < 8; ++i) acc[i] = (f32x4){0,0,0,0};

  uint4 c0 = *reinterpret_cast<const uint4*>(apk + 0);
  uint4 c1 = *reinterpret_cast<const uint4*>(apk + 1024);

  #pragma unroll
  for (int kc = 0; kc < 8; ++kc) {
    uint4 n0, n1;
    if (kc < 7) {
      n0 = *reinterpret_cast<const uint4*>(apk + (kc+1)*2048);
      n1 = *reinterpret_cast<const uint4*>(apk + (kc+1)*2048 + 1024);
    }
    f16x8 a0 = u4_to_f16x8(c0);   // ks=0 (waits vmcnt(2): only current pair)
    f16x8 a1 = u4_to_f16x8(c1);   // ks=1
    #pragma unroll
    for (int nt = 0; nt < 8; ++nt) {
      uint4 rb = *reinterpret_cast<const uint4*>(wlds + ((kc*2 + 0)*8 + nt)*1024);
      acc[nt] = __builtin_amdgcn_mfma_f32_16x16x32_f16(a0, u4_to_f16x8(rb), acc[nt], 0, 0, 0);
    }
    #pragma unroll
    for (int nt = 0; nt < 8; ++nt) {
      uint4 rb = *reinterpret_cast<const uint4*>(wlds + ((kc*2 + 1)*8 + nt)*1024);
      acc[nt] = __builtin_amdgcn_mfma_f32_16x16x32_f16(a1, u4_to_f16x8(rb), acc[nt], 0, 0, 0);
    }
    if (kc < 7) { c0 = n0; c1 = n1; }
  }

  {
    f16x8 a2;
    const int pb0 = wave*16 + lr + lg*8;
    #pragma unroll
    for (int j = 0; j < 8; ++j)
      a2[j] = __builtin_bit_cast(_Float16, f2h(sPrev[pb0 + j]));
    const char* mlds = (const char*)sMT + lr*64 + lg*16;
    #pragma unroll
    for (int nt = 0; nt < 8; ++nt) {
      uint4 mv = *reinterpret_cast<const uint4*>(mlds + nt*1024);
      acc[nt] = __builtin_amdgcn_mfma_f32_16x16x32_f16(a2, u4_to_f16x8(mv), acc[nt], 0, 0, 0);
    }
  }

  {
    float es0 = 0.f, es1 = 0.f, es2 = 0.f, es3 = 0.f;
    #pragma unroll
    for (int nt = 0; nt < 8; ++nt) {
      float dh = sDecb[nt*16 + lr];
      float wo = sWout[nt*16 + lr];
      es0 += fast_tanh(acc[nt][0] + dh) * wo;
      es1 += fast_tanh(acc[nt][1] + dh) * wo;
      es2 += fast_tanh(acc[nt][2] + dh) * wo;
      es3 += fast_tanh(acc[nt][3] + dh) * wo;
    }
    #pragma unroll
    for (int off = 1; off < 16; off <<= 1) {
      es0 += __shfl_xor(es0, off, 64);
      es1 += __shfl_xor(es1, off, 64);
      es2 += __shfl_xor(es2, off, 64);
      es3 += __shfl_xor(es3, off, 64);
    }
    if (lr == 0) {
      const int t = t0 + wave*16 + lg*4;
      float ev[4] = {es0, es1, es2, es3};
      #pragma unroll
      for (int r = 0; r < 4; ++r)
        if (t + r < 2000) energy[b*2000 + t + r] = ev[r];
    }
  }
}

// ---------------- energy (fallback, r11 exact) ----------------
__global__ __launch_bounds__(1024, 4) void energy_kernel(
    const float* __restrict__ enc, const float* __restrict__ prev,
    const unsigned short* __restrict__ WTpack, const unsigned short* __restrict__ MTg,
    const float* __restrict__ decb, const float* __restrict__ W_out,
    float* __restrict__ energy)
{
  extern __shared__ __align__(16) char smem[];
  unsigned short* sWT = (unsigned short*)smem;
  unsigned short* sMT = (unsigned short*)(smem + 131072);
  float* sPrev = (float*)(smem + 139264);
  float* sDecb = (float*)(smem + 140416);
  float* sWout = (float*)(smem + 140928);

  const int b  = blockIdx.y;
  const int t0 = blockIdx.x * 256;
  const int tid = threadIdx.x;
  const int wave = tid >> 6, lane = tid & 63;
  const int lr = lane & 15, lg = lane >> 4;

  {
    const uint4* wsrc = (const uint4*)WTpack;
    uint4* wdst = (uint4*)sWT;
    #pragma unroll
    for (int i = 0; i < 8; ++i) wdst[tid + i*1024] = wsrc[tid + i*1024];
    if (tid < 512) ((uint4*)sMT)[tid] = ((const uint4*)MTg)[tid];
    if (tid < 288) {
      int tt = t0 + tid - 15;
      sPrev[tid] = (tt >= 0 && tt < 2000) ? prev[b*2000 + tt] : 0.f;
    }
    if (tid < 128) { sDecb[tid] = decb[b*128 + tid]; sWout[tid] = W_out[tid]; }
  }
  __syncthreads();

  const float* encB = enc + (size_t)b * (2000u*512u);
  int tg = t0 + wave*16 + lr; if (tg > 1999) tg = 1999;
  const float* rowp = encB + (size_t)tg*512 + lg*8;
  const char* wlds = (const char*)sWT + lane*16;

  f32x4 acc[8];
  #pragma unroll
  for (int i = 0; i < 8; ++i) acc[i] = (f32x4){0,0,0,0};

  float4 c0 = *reinterpret_cast<const float4*>(rowp + 0);
  float4 c1 = *reinterpret_cast<const float4*>(rowp + 4);
  float4 c2 = *reinterpret_cast<const float4*>(rowp + 32);
  float4 c3 = *reinterpret_cast<const float4*>(rowp + 36);

  #pragma unroll
  for (int kc = 0; kc < 8; ++kc) {
    float4 n0, n1, n2, n3;
    if (kc < 7) {
      const float* p = rowp + (kc+1)*64;
      n0 = *reinterpret_cast<const float4*>(p + 0);
      n1 = *reinterpret_cast<const float4*>(p + 4);
      n2 = *reinterpret_cast<const float4*>(p + 32);
      n3 = *reinterpret_cast<const float4*>(p + 36);
    }
    f16x8 a0 = cvt8(c0, c1);
    f16x8 a1 = cvt8(c2, c3);
    #pragma unroll
    for (int nt = 0; nt < 8; ++nt) {
      uint4 rb = *reinterpret_cast<const uint4*>(wlds + ((kc*2 + 0)*8 + nt)*1024);
      acc[nt] = __builtin_amdgcn_mfma_f32_16x16x32_f16(a0, u4_to_f16x8(rb), acc[nt], 0, 0, 0);
    }
    #pragma unroll
    for (int nt = 0; nt < 8; ++nt) {
      uint4 rb = *reinterpret_cast<const uint4*>(wlds + ((kc*2 + 1)*8 + nt)*1024);
      acc[nt] = __builtin_amdgcn_mfma_f32_16x16x32_f16(a1, u4_to_f16x8(rb), acc[nt], 0, 0, 0);
    }
    if (kc < 7) { c0 = n0; c1 = n1; c2 = n2; c3 = n3; }
  }

  {
    f16x8 a2;
    const int pb0 = wave*16 + lr + lg*8;
    #pragma unroll
    for (int j = 0; j < 8; ++j)
      a2[j] = __builtin_bit_cast(_Float16, f2h(sPrev[pb0 + j]));
    const char* mlds = (const char*)sMT + lr*64 + lg*16;
    #pragma unroll
    for (int nt = 0; nt < 8; ++nt) {
      uint4 mv = *reinterpret_cast<const uint4*>(mlds + nt*1024);
      acc[nt] = __builtin_amdgcn_mfma_f32_16x16x32_f16(a2, u4_to_f16x8(mv), acc[nt], 0, 0, 0);
    }
  }

  {
    float es0 = 0.f, es1 = 0.f, es2 = 0.f, es3 = 0.f;
    #pragma unroll
    for (int nt = 0; nt < 8; ++nt) {
      float dh = sDecb[nt*16 + lr];
      float wo = sWout[nt*16 + lr];
      es0 += fast_tanh(acc[nt][0] + dh) * wo;
      es1 += fast_tanh(acc[nt][1] + dh) * wo;
      es2 += fast_tanh(acc[nt][2] + dh) * wo;
      es3 += fast_tanh(acc[nt][3] + dh) * wo;
    }
    #pragma unroll
    for (int off = 1; off < 16; off <<= 1) {
      es0 += __shfl_xor(es0, off, 64);
      es1 += __shfl_xor(es1, off, 64);
      es2 += __shfl_xor(es2, off, 64);
      es3 += __shfl_xor(es3, off, 64);
    }
    if (lr == 0) {
      const int t = t0 + wave*16 + lg*4;
      float ev[4] = {es0, es1, es2, es3};
      #pragma unroll
      for (int r = 0; r < 4; ++r)
        if (t + r < 2000) energy[b*2000 + t + r] = ev[r];
    }
  }
}

// ---------------- softmax over T per b -> att_w ----------------
__global__ __launch_bounds__(256) void softmax_kernel(
    const float* __restrict__ energy, float* __restrict__ attw)
{
  const int b = blockIdx.x, tid = threadIdx.x;
  __shared__ float red[4];
  __shared__ float red2[4];
  float m = -1e30f;
  for (int i = tid; i < 2000; i += 256) m = fmaxf(m, energy[b*2000 + i]);
  #pragma unroll
  for (int off = 1; off < 64; off <<= 1) m = fmaxf(m, __shfl_xor(m, off, 64));
  if ((tid & 63) == 0) red[tid >> 6] = m;
  __syncthreads();
  m = fmaxf(fmaxf(red[0], red[1]), fmaxf(red[2], red[3]));

  float s = 0.f;
  for (int i = tid; i < 2000; i += 256) {
    float p = __expf(energy[b*2000 + i] - m);
    attw[b*2000 + i] = p;
    s += p;
  }
  #pragma unroll
  for (int off = 1; off < 64; off <<= 1) s += __shfl_xor(s, off, 64);
  if ((tid & 63) == 0) red2[tid >> 6] = s;
  __syncthreads();
  s = red2[0] + red2[1] + red2[2] + red2[3];
  float inv = 1.f / s;
  for (int i = tid; i < 2000; i += 256) attw[b*2000 + i] *= inv;
}

// ---------------- att_c partials ----------------
__global__ __launch_bounds__(256) void attc_partial_kernel(
    const float* __restrict__ enc, const float* __restrict__ attw,
    float* __restrict__ part)
{
  const int b = blockIdx.y, ch = blockIdx.x, tid = threadIdx.x;
  const int p = tid >> 7;
  const int e4 = (tid & 127) * 4;
  const int tstart = ch * 125 + p, tend = ch * 125 + 125;
  const float* encB = enc + (size_t)b * (2000u*512u);
  float a0 = 0.f, a1 = 0.f, a2 = 0.f, a3 = 0.f;
  #pragma unroll 2
  for (int t = tstart; t < tend; t += 2) {
    float w = attw[b*2000 + t];
    float4 v = *reinterpret_cast<const float4*>(encB + (size_t)t*512 + e4);
    a0 = fmaf(v.x, w, a0);
    a1 = fmaf(v.y, w, a1);
    a2 = fmaf(v.z, w, a2);
    a3 = fmaf(v.w, w, a3);
  }
  float4 out = {a0, a1, a2, a3};
  *reinterpret_cast<float4*>(part + ((size_t)(b*32 + ch*2 + p))*512 + e4) = out;
}

__global__ __launch_bounds__(128) void attc_reduce_kernel(
    const float* __restrict__ part, float* __restrict__ out)
{
  const int b = blockIdx.x, e4 = threadIdx.x * 4;
  float4 s = {0.f, 0.f, 0.f, 0.f};
  #pragma unroll
  for (int c = 0; c < 32; ++c) {
    float4 v = *reinterpret_cast<const float4*>(part + ((size_t)(b*32 + c))*512 + e4);
    s.x += v.x; s.y += v.y; s.z += v.z; s.w += v.w;
  }
  *reinterpret_cast<float4*>(out + b*512 + e4) = s;
}

// ---------------- launch ----------------
extern "C" void kernel_launch(void* const* d_in, const int* in_sizes, int n_in,
                              void* d_out, int out_size, void* d_ws, size_t ws_size,
                              hipStream_t stream) {
  (void)in_sizes; (void)n_in; (void)out_size;
  const float* enc       = (const float*)d_in[0];
  const float* dec_state = (const float*)d_in[2];
  const float* prev      = (const float*)d_in[3];
  const float* W_enc     = (const float*)d_in[4];
  const float* b_enc     = (const float*)d_in[5];
  const float* W_dec     = (const float*)d_in[6];
  const float* W_att     = (const float*)d_in[7];
  const float* conv_w    = (const float*)d_in[8];
  const float* W_out     = (const float*)d_in[9];

  char* ws = (char*)d_ws;
  float*          energy = (float*)(ws + 0);               // 524288
  float*          decb   = (float*)(ws + 524288);          // 32768
  unsigned short* MTg    = (unsigned short*)(ws + 557056); // 8192
  unsigned short* WTpack = (unsigned short*)(ws + 565248); // 131072
  float*          part   = (float*)(ws + 696320);          // 4194304
  unsigned short* PK     = (unsigned short*)(ws + 4890624);// 134217728

  const size_t need_pk = 4890624ull + 134217728ull;

  float* attc = (float*)d_out;             // (64, 512)
  float* attw = (float*)d_out + 64*512;    // (64, 2000)

  const int lds_bytes = 141440;

  prep_kernel<<<97, 256, 0, stream>>>(dec_state, W_dec, b_enc, conv_w, W_att, W_enc,
                                      decb, MTg, WTpack);
  if (ws_size >= need_pk) {
    pack_kernel     <<<dim3(8, 64), 256, 0, stream>>>(enc, PK);
    energy_pk_kernel<<<dim3(8, 64), 1024, lds_bytes, stream>>>(PK, prev, WTpack, MTg, decb, W_out, energy);
  } else {
    energy_kernel   <<<dim3(8, 64), 1024, lds_bytes, stream>>>(enc, prev, WTpack, MTg, decb, W_out, energy);
  }
  softmax_kernel     <<<64, 256, 0, stream>>>(energy, attw);
  attc_partial_kernel<<<dim3(16, 64), 256, 0, stream>>>(enc, attw, part);
  attc_reduce_kernel <<<64, 128, 0, stream>>>(part, attc);
}

// Round 16
// 231.509 us; speedup vs baseline: 1.1621x; 1.1621x over previous
//
#include <hip/hip_runtime.h>
#include <hip/hip_fp16.h>

typedef _Float16 f16x8 __attribute__((ext_vector_type(8)));
typedef float f32x4 __attribute__((ext_vector_type(4)));

// B=64, T=2000, E=512, D=1024, CC=32, K=31, H=128, PAD=15

__device__ __forceinline__ unsigned short f2h(float f) {
  __half h = __float2half(f);   // v_cvt_f16_f32, RNE
  return __builtin_bit_cast(unsigned short, h);
}

__device__ __forceinline__ f16x8 u4_to_f16x8(uint4 v) {
  return __builtin_bit_cast(f16x8, v);
}

__device__ __forceinline__ f16x8 cvt8(float4 u, float4 v) {
  uint4 w;
  w.x = ((unsigned)f2h(u.y) << 16) | f2h(u.x);
  w.y = ((unsigned)f2h(u.w) << 16) | f2h(u.z);
  w.z = ((unsigned)f2h(v.y) << 16) | f2h(v.x);
  w.w = ((unsigned)f2h(v.w) << 16) | f2h(v.z);
  return u4_to_f16x8(w);
}

__device__ __forceinline__ float fast_tanh(float x) {
  return 1.f - 2.f / (__expf(2.f * x) + 1.f);
}

// ---------------- misc prep: decb (fp32), MTg, WTpack (unchanged r11) ----------------
__global__ __launch_bounds__(256) void prep_kernel(
    const float* __restrict__ dec_state, const float* __restrict__ W_dec,
    const float* __restrict__ b_enc, const float* __restrict__ conv_w,
    const float* __restrict__ W_att, const float* __restrict__ W_enc,
    float* __restrict__ decb, unsigned short* __restrict__ MTg,
    unsigned short* __restrict__ WTpack)
{
  const int blk = blockIdx.x, tid = threadIdx.x;
  if (blk < 32) {
    __shared__ float sd[2048];
    const int sub = tid >> 7, h = tid & 127;
    const int b = blk*2 + sub;
    for (int i = h; i < 1024; i += 128) sd[sub*1024 + i] = dec_state[b*1024 + i];
    __syncthreads();
    float acc = b_enc[h];
    #pragma unroll 8
    for (int d = 0; d < 1024; ++d) acc = fmaf(sd[sub*1024 + d], W_dec[d*128 + h], acc);
    decb[b*128 + h] = acc;
  } else if (blk < 96) {
    const int e0 = (blk - 32) * 8;
    #pragma unroll
    for (int jj = 0; jj < 4; ++jj) {
      int idx = tid + jj*256;
      int el = idx >> 7, hh = idx & 127;
      int e = e0 + el;
      int kc = e >> 6, ks = (e >> 5) & 1, lg = (e >> 3) & 3, j = e & 7;
      int nt = hh >> 4, lr = hh & 15;
      int dst = (((kc*2 + ks)*8 + nt)*64 + lg*16 + lr)*8 + j;
      WTpack[dst] = f2h(W_enc[e*128 + hh]);
    }
  } else {
    if (tid < 128) {
      const int h = tid;
      for (int k = 0; k < 31; ++k) {
        float a = 0.f;
        #pragma unroll
        for (int c = 0; c < 32; ++c) a = fmaf(conv_w[c*31 + k], W_att[c*128 + h], a);
        MTg[h*32 + k] = f2h(a);
      }
      MTg[h*32 + 31] = 0;
    }
  }
}

// ---------------- pack v2: coalesced read -> LDS transpose -> COALESCED PK write ----------------
// Same PK layout as r15 (bit-verified): PK[(b*128+frag)*16384 + kc*2048 + ks*1024 + (lg*16+lr)*16 + jh*2]
// frag = t>>4, lr = t&15, e = kc*64+ks*32+lg*8+j. LDS image group-padded: phys = (W>>10)*1040 + (W&1023).
__global__ __launch_bounds__(256) void pack_kernel(
    const float* __restrict__ enc, unsigned short* __restrict__ PK)
{
  __shared__ __align__(16) char sbuf[64*1040];   // 66560 B (64 groups of 1KB, +16B pad each)
  const int b  = blockIdx.y;
  const int r0 = blockIdx.x * 128;               // 16 blocks per b
  const int tid = threadIdx.x;
  const float* encB = enc + (size_t)b * (2000u*512u);
  const int e4 = (tid & 127) * 4;
  const int kc = e4 >> 6, ks = (e4 >> 5) & 1, lg = (e4 >> 3) & 3, jh = e4 & 7;
  const int half = tid >> 7;

  #pragma unroll 1
  for (int s = 0; s < 2; ++s) {
    const int rs = r0 + s*64;
    // phase A: coalesced row read, cvt, scattered LDS write (group-padded)
    #pragma unroll 4
    for (int i = 0; i < 32; ++i) {
      int lrow = 2*i + half;                     // 0..63
      int grow = rs + lrow;
      int src = grow > 1999 ? 1999 : grow;       // clamp, same as r15
      float4 v = *reinterpret_cast<const float4*>(encB + (size_t)src*512 + e4);
      uint2 wv;
      wv.x = ((unsigned)f2h(v.y) << 16) | f2h(v.x);
      wv.y = ((unsigned)f2h(v.w) << 16) | f2h(v.z);
      int W = (lrow >> 4)*16384 + kc*2048 + ks*1024 + (lg*16 + (lrow & 15))*16 + jh*2;
      *reinterpret_cast<uint2*>(sbuf + (W >> 10)*1040 + (W & 1023)) = wv;
    }
    __syncthreads();
    // phase B: linear LDS read, fully-coalesced global write (1KB contiguous per wave)
    char* dst = (char*)PK + (size_t)(b*128 + (rs >> 4)) * 16384;
    #pragma unroll 4
    for (int j = 0; j < 16; ++j) {
      int lin = j*4096 + tid*16;
      uint4 v = *reinterpret_cast<const uint4*>(sbuf + (lin >> 10)*1040 + (lin & 1023));
      *reinterpret_cast<uint4*>(dst + lin) = v;
    }
    __syncthreads();
  }
}

// ---------------- energy (PK) v2: 512 rows/block (grid=256=1/CU), 2 passes, 2-ahead A prefetch ----------------
__global__ __launch_bounds__(1024, 4) void energy_pk_kernel(
    const unsigned short* __restrict__ PK, const float* __restrict__ prev,
    const unsigned short* __restrict__ WTpack, const unsigned short* __restrict__ MTg,
    const float* __restrict__ decb, const float* __restrict__ W_out,
    float* __restrict__ energy)
{
  extern __shared__ __align__(16) char smem[];
  unsigned short* sWT = (unsigned short*)smem;              // 131072 B
  unsigned short* sMT = (unsigned short*)(smem + 131072);   // 8192 B
  float* sPrev = (float*)(smem + 139264);                   // 1152 B
  float* sDecb = (float*)(smem + 140416);
  float* sWout = (float*)(smem + 140928);

  const int b  = blockIdx.y;
  const int tid = threadIdx.x;
  const int wave = tid >> 6, lane = tid & 63;
  const int lr = lane & 15, lg = lane >> 4;

  {
    const uint4* wsrc = (const uint4*)WTpack;
    uint4* wdst = (uint4*)sWT;
    #pragma unroll
    for (int i = 0; i < 8; ++i) wdst[tid + i*1024] = wsrc[tid + i*1024];
    if (tid < 512) ((uint4*)sMT)[tid] = ((const uint4*)MTg)[tid];
    if (tid < 288) {
      int tt = blockIdx.x*512 + tid - 15;
      sPrev[tid] = (tt >= 0 && tt < 2000) ? prev[b*2000 + tt] : 0.f;
    }
    if (tid < 128) { sDecb[tid] = decb[b*128 + tid]; sWout[tid] = W_out[tid]; }
  }
  __syncthreads();

  const char* wlds = (const char*)sWT + lane*16;

  #pragma unroll 1
  for (int p = 0; p < 2; ++p) {
    const int t0 = blockIdx.x*512 + p*256;
    if (p == 1) {
      __syncthreads();   // all pass-0 sPrev reads done
      if (tid < 288) {
        int tt = t0 + tid - 15;
        sPrev[tid] = (tt >= 0 && tt < 2000) ? prev[b*2000 + tt] : 0.f;
      }
      __syncthreads();
    }

    const char* apk = (const char*)PK + (size_t)(b*128 + (t0 >> 4) + wave)*16384 + lane*16;

    f32x4 acc[8];
    #pragma unroll
    for (int i = 0; i < 8; ++i) acc[i] = (f32x4){0,0,0,0};

    // 2-ahead prefetch: pairs for kc, kc+1 live; issue kc+2 in loop
    uint4 c0 = *reinterpret_cast<const uint4*>(apk + 0);
    uint4 c1 = *reinterpret_cast<const uint4*>(apk + 1024);
    uint4 d0 = *reinterpret_cast<const uint4*>(apk + 2048);
    uint4 d1 = *reinterpret_cast<const uint4*>(apk + 3072);

    #pragma unroll
    for (int kc = 0; kc < 8; ++kc) {
      uint4 n0, n1;
      if (kc < 6) {
        n0 = *reinterpret_cast<const uint4*>(apk + (kc+2)*2048);
        n1 = *reinterpret_cast<const uint4*>(apk + (kc+2)*2048 + 1024);
      }
      f16x8 a0 = u4_to_f16x8(c0);   // ks=0 (waits vmcnt(4): two younger pairs in flight)
      f16x8 a1 = u4_to_f16x8(c1);   // ks=1
      #pragma unroll
      for (int nt = 0; nt < 8; ++nt) {
        uint4 rb = *reinterpret_cast<const uint4*>(wlds + ((kc*2 + 0)*8 + nt)*1024);
        acc[nt] = __builtin_amdgcn_mfma_f32_16x16x32_f16(a0, u4_to_f16x8(rb), acc[nt], 0, 0, 0);
      }
      #pragma unroll
      for (int nt = 0; nt < 8; ++nt) {
        uint4 rb = *reinterpret_cast<const uint4*>(wlds + ((kc*2 + 1)*8 + nt)*1024);
        acc[nt] = __builtin_amdgcn_mfma_f32_16x16x32_f16(a1, u4_to_f16x8(rb), acc[nt], 0, 0, 0);
      }
      c0 = d0; c1 = d1;
      if (kc < 6) { d0 = n0; d1 = n1; }
    }

    // conv as MFMA (identical math to r11-r15)
    {
      f16x8 a2;
      const int pb0 = wave*16 + lr + lg*8;
      #pragma unroll
      for (int j = 0; j < 8; ++j)
        a2[j] = __builtin_bit_cast(_Float16, f2h(sPrev[pb0 + j]));
      const char* mlds = (const char*)sMT + lr*64 + lg*16;
      #pragma unroll
      for (int nt = 0; nt < 8; ++nt) {
        uint4 mv = *reinterpret_cast<const uint4*>(mlds + nt*1024);
        acc[nt] = __builtin_amdgcn_mfma_f32_16x16x32_f16(a2, u4_to_f16x8(mv), acc[nt], 0, 0, 0);
      }
    }

    // epilogue
    {
      float es0 = 0.f, es1 = 0.f, es2 = 0.f, es3 = 0.f;
      #pragma unroll
      for (int nt = 0; nt < 8; ++nt) {
        float dh = sDecb[nt*16 + lr];
        float wo = sWout[nt*16 + lr];
        es0 += fast_tanh(acc[nt][0] + dh) * wo;
        es1 += fast_tanh(acc[nt][1] + dh) * wo;
        es2 += fast_tanh(acc[nt][2] + dh) * wo;
        es3 += fast_tanh(acc[nt][3] + dh) * wo;
      }
      #pragma unroll
      for (int off = 1; off < 16; off <<= 1) {
        es0 += __shfl_xor(es0, off, 64);
        es1 += __shfl_xor(es1, off, 64);
        es2 += __shfl_xor(es2, off, 64);
        es3 += __shfl_xor(es3, off, 64);
      }
      if (lr == 0) {
        const int t = t0 + wave*16 + lg*4;
        float ev[4] = {es0, es1, es2, es3};
        #pragma unroll
        for (int r = 0; r < 4; ++r)
          if (t + r < 2000) energy[b*2000 + t + r] = ev[r];
      }
    }
  }
}

// ---------------- energy (fallback, r11 exact) ----------------
__global__ __launch_bounds__(1024, 4) void energy_kernel(
    const float* __restrict__ enc, const float* __restrict__ prev,
    const unsigned short* __restrict__ WTpack, const unsigned short* __restrict__ MTg,
    const float* __restrict__ decb, const float* __restrict__ W_out,
    float* __restrict__ energy)
{
  extern __shared__ __align__(16) char smem[];
  unsigned short* sWT = (unsigned short*)smem;
  unsigned short* sMT = (unsigned short*)(smem + 131072);
  float* sPrev = (float*)(smem + 139264);
  float* sDecb = (float*)(smem + 140416);
  float* sWout = (float*)(smem + 140928);

  const int b  = blockIdx.y;
  const int t0 = blockIdx.x * 256;
  const int tid = threadIdx.x;
  const int wave = tid >> 6, lane = tid & 63;
  const int lr = lane & 15, lg = lane >> 4;

  {
    const uint4* wsrc = (const uint4*)WTpack;
    uint4* wdst = (uint4*)sWT;
    #pragma unroll
    for (int i = 0; i < 8; ++i) wdst[tid + i*1024] = wsrc[tid + i*1024];
    if (tid < 512) ((uint4*)sMT)[tid] = ((const uint4*)MTg)[tid];
    if (tid < 288) {
      int tt = t0 + tid - 15;
      sPrev[tid] = (tt >= 0 && tt < 2000) ? prev[b*2000 + tt] : 0.f;
    }
    if (tid < 128) { sDecb[tid] = decb[b*128 + tid]; sWout[tid] = W_out[tid]; }
  }
  __syncthreads();

  const float* encB = enc + (size_t)b * (2000u*512u);
  int tg = t0 + wave*16 + lr; if (tg > 1999) tg = 1999;
  const float* rowp = encB + (size_t)tg*512 + lg*8;
  const char* wlds = (const char*)sWT + lane*16;

  f32x4 acc[8];
  #pragma unroll
  for (int i = 0; i < 8; ++i) acc[i] = (f32x4){0,0,0,0};

  float4 c0 = *reinterpret_cast<const float4*>(rowp + 0);
  float4 c1 = *reinterpret_cast<const float4*>(rowp + 4);
  float4 c2 = *reinterpret_cast<const float4*>(rowp + 32);
  float4 c3 = *reinterpret_cast<const float4*>(rowp + 36);

  #pragma unroll
  for (int kc = 0; kc < 8; ++kc) {
    float4 n0, n1, n2, n3;
    if (kc < 7) {
      const float* p = rowp + (kc+1)*64;
      n0 = *reinterpret_cast<const float4*>(p + 0);
      n1 = *reinterpret_cast<const float4*>(p + 4);
      n2 = *reinterpret_cast<const float4*>(p + 32);
      n3 = *reinterpret_cast<const float4*>(p + 36);
    }
    f16x8 a0 = cvt8(c0, c1);
    f16x8 a1 = cvt8(c2, c3);
    #pragma unroll
    for (int nt = 0; nt < 8; ++nt) {
      uint4 rb = *reinterpret_cast<const uint4*>(wlds + ((kc*2 + 0)*8 + nt)*1024);
      acc[nt] = __builtin_amdgcn_mfma_f32_16x16x32_f16(a0, u4_to_f16x8(rb), acc[nt], 0, 0, 0);
    }
    #pragma unroll
    for (int nt = 0; nt < 8; ++nt) {
      uint4 rb = *reinterpret_cast<const uint4*>(wlds + ((kc*2 + 1)*8 + nt)*1024);
      acc[nt] = __builtin_amdgcn_mfma_f32_16x16x32_f16(a1, u4_to_f16x8(rb), acc[nt], 0, 0, 0);
    }
    if (kc < 7) { c0 = n0; c1 = n1; c2 = n2; c3 = n3; }
  }

  {
    f16x8 a2;
    const int pb0 = wave*16 + lr + lg*8;
    #pragma unroll
    for (int j = 0; j < 8; ++j)
      a2[j] = __builtin_bit_cast(_Float16, f2h(sPrev[pb0 + j]));
    const char* mlds = (const char*)sMT + lr*64 + lg*16;
    #pragma unroll
    for (int nt = 0; nt < 8; ++nt) {
      uint4 mv = *reinterpret_cast<const uint4*>(mlds + nt*1024);
      acc[nt] = __builtin_amdgcn_mfma_f32_16x16x32_f16(a2, u4_to_f16x8(mv), acc[nt], 0, 0, 0);
    }
  }

  {
    float es0 = 0.f, es1 = 0.f, es2 = 0.f, es3 = 0.f;
    #pragma unroll
    for (int nt = 0; nt < 8; ++nt) {
      float dh = sDecb[nt*16 + lr];
      float wo = sWout[nt*16 + lr];
      es0 += fast_tanh(acc[nt][0] + dh) * wo;
      es1 += fast_tanh(acc[nt][1] + dh) * wo;
      es2 += fast_tanh(acc[nt][2] + dh) * wo;
      es3 += fast_tanh(acc[nt][3] + dh) * wo;
    }
    #pragma unroll
    for (int off = 1; off < 16; off <<= 1) {
      es0 += __shfl_xor(es0, off, 64);
      es1 += __shfl_xor(es1, off, 64);
      es2 += __shfl_xor(es2, off, 64);
      es3 += __shfl_xor(es3, off, 64);
    }
    if (lr == 0) {
      const int t = t0 + wave*16 + lg*4;
      float ev[4] = {es0, es1, es2, es3};
      #pragma unroll
      for (int r = 0; r < 4; ++r)
        if (t + r < 2000) energy[b*2000 + t + r] = ev[r];
    }
  }
}

// ---------------- softmax over T per b -> att_w ----------------
__global__ __launch_bounds__(256) void softmax_kernel(
    const float* __restrict__ energy, float* __restrict__ attw)
{
  const int b = blockIdx.x, tid = threadIdx.x;
  __shared__ float red[4];
  __shared__ float red2[4];
  float m = -1e30f;
  for (int i = tid; i < 2000; i += 256) m = fmaxf(m, energy[b*2000 + i]);
  #pragma unroll
  for (int off = 1; off < 64; off <<= 1) m = fmaxf(m, __shfl_xor(m, off, 64));
  if ((tid & 63) == 0) red[tid >> 6] = m;
  __syncthreads();
  m = fmaxf(fmaxf(red[0], red[1]), fmaxf(red[2], red[3]));

  float s = 0.f;
  for (int i = tid; i < 2000; i += 256) {
    float p = __expf(energy[b*2000 + i] - m);
    attw[b*2000 + i] = p;
    s += p;
  }
  #pragma unroll
  for (int off = 1; off < 64; off <<= 1) s += __shfl_xor(s, off, 64);
  if ((tid & 63) == 0) red2[tid >> 6] = s;
  __syncthreads();
  s = red2[0] + red2[1] + red2[2] + red2[3];
  float inv = 1.f / s;
  for (int i = tid; i < 2000; i += 256) attw[b*2000 + i] *= inv;
}

// ---------------- att_c partials ----------------
__global__ __launch_bounds__(256) void attc_partial_kernel(
    const float* __restrict__ enc, const float* __restrict__ attw,
    float* __restrict__ part)
{
  const int b = blockIdx.y, ch = blockIdx.x, tid = threadIdx.x;
  const int p = tid >> 7;
  const int e4 = (tid & 127) * 4;
  const int tstart = ch * 125 + p, tend = ch * 125 + 125;
  const float* encB = enc + (size_t)b * (2000u*512u);
  float a0 = 0.f, a1 = 0.f, a2 = 0.f, a3 = 0.f;
  #pragma unroll 2
  for (int t = tstart; t < tend; t += 2) {
    float w = attw[b*2000 + t];
    float4 v = *reinterpret_cast<const float4*>(encB + (size_t)t*512 + e4);
    a0 = fmaf(v.x, w, a0);
    a1 = fmaf(v.y, w, a1);
    a2 = fmaf(v.z, w, a2);
    a3 = fmaf(v.w, w, a3);
  }
  float4 out = {a0, a1, a2, a3};
  *reinterpret_cast<float4*>(part + ((size_t)(b*32 + ch*2 + p))*512 + e4) = out;
}

__global__ __launch_bounds__(128) void attc_reduce_kernel(
    const float* __restrict__ part, float* __restrict__ out)
{
  const int b = blockIdx.x, e4 = threadIdx.x * 4;
  float4 s = {0.f, 0.f, 0.f, 0.f};
  #pragma unroll
  for (int c = 0; c < 32; ++c) {
    float4 v = *reinterpret_cast<const float4*>(part + ((size_t)(b*32 + c))*512 + e4);
    s.x += v.x; s.y += v.y; s.z += v.z; s.w += v.w;
  }
  *reinterpret_cast<float4*>(out + b*512 + e4) = s;
}

// ---------------- launch ----------------
extern "C" void kernel_launch(void* const* d_in, const int* in_sizes, int n_in,
                              void* d_out, int out_size, void* d_ws, size_t ws_size,
                              hipStream_t stream) {
  (void)in_sizes; (void)n_in; (void)out_size;
  const float* enc       = (const float*)d_in[0];
  const float* dec_state = (const float*)d_in[2];
  const float* prev      = (const float*)d_in[3];
  const float* W_enc     = (const float*)d_in[4];
  const float* b_enc     = (const float*)d_in[5];
  const float* W_dec     = (const float*)d_in[6];
  const float* W_att     = (const float*)d_in[7];
  const float* conv_w    = (const float*)d_in[8];
  const float* W_out     = (const float*)d_in[9];

  char* ws = (char*)d_ws;
  float*          energy = (float*)(ws + 0);               // 524288
  float*          decb   = (float*)(ws + 524288);          // 32768
  unsigned short* MTg    = (unsigned short*)(ws + 557056); // 8192
  unsigned short* WTpack = (unsigned short*)(ws + 565248); // 131072
  float*          part   = (float*)(ws + 696320);          // 4194304
  unsigned short* PK     = (unsigned short*)(ws + 4890624);// 134217728

  const size_t need_pk = 4890624ull + 134217728ull;

  float* attc = (float*)d_out;             // (64, 512)
  float* attw = (float*)d_out + 64*512;    // (64, 2000)

  const int lds_bytes = 141440;

  prep_kernel<<<97, 256, 0, stream>>>(dec_state, W_dec, b_enc, conv_w, W_att, W_enc,
                                      decb, MTg, WTpack);
  if (ws_size >= need_pk) {
    pack_kernel     <<<dim3(16, 64), 256, 0, stream>>>(enc, PK);
    energy_pk_kernel<<<dim3(4, 64), 1024, lds_bytes, stream>>>(PK, prev, WTpack, MTg, decb, W_out, energy);
  } else {
    energy_kernel   <<<dim3(8, 64), 1024, lds_bytes, stream>>>(enc, prev, WTpack, MTg, decb, W_out, energy);
  }
  softmax_kernel     <<<64, 256, 0, stream>>>(energy, attw);
  attc_partial_kernel<<<dim3(16, 64), 256, 0, stream>>>(enc, attw, part);
  attc_reduce_kernel <<<64, 128, 0, stream>>>(part, attc);
}

// Round 17
// 217.526 us; speedup vs baseline: 1.2368x; 1.0643x over previous
//
#include <hip/hip_runtime.h>
#include <hip/hip_fp16.h>

typedef _Float16 f16x8 __attribute__((ext_vector_type(8)));
typedef float f32x4 __attribute__((ext_vector_type(4)));

// B=64, T=2000, E=512, D=1024, CC=32, K=31, H=128, PAD=15

__device__ __forceinline__ unsigned short f2h(float f) {
  __half h = __float2half(f);   // v_cvt_f16_f32, RNE
  return __builtin_bit_cast(unsigned short, h);
}

__device__ __forceinline__ f16x8 u4_to_f16x8(uint4 v) {
  return __builtin_bit_cast(f16x8, v);
}

__device__ __forceinline__ float fast_tanh(float x) {
  return 1.f - 2.f / (__expf(2.f * x) + 1.f);
}

// ---------------- misc prep: decb (fp32), MTg, WTpack (unchanged r11) ----------------
__global__ __launch_bounds__(256) void prep_kernel(
    const float* __restrict__ dec_state, const float* __restrict__ W_dec,
    const float* __restrict__ b_enc, const float* __restrict__ conv_w,
    const float* __restrict__ W_att, const float* __restrict__ W_enc,
    float* __restrict__ decb, unsigned short* __restrict__ MTg,
    unsigned short* __restrict__ WTpack)
{
  const int blk = blockIdx.x, tid = threadIdx.x;
  if (blk < 32) {
    __shared__ float sd[2048];
    const int sub = tid >> 7, h = tid & 127;
    const int b = blk*2 + sub;
    for (int i = h; i < 1024; i += 128) sd[sub*1024 + i] = dec_state[b*1024 + i];
    __syncthreads();
    float acc = b_enc[h];
    #pragma unroll 8
    for (int d = 0; d < 1024; ++d) acc = fmaf(sd[sub*1024 + d], W_dec[d*128 + h], acc);
    decb[b*128 + h] = acc;
  } else if (blk < 96) {
    const int e0 = (blk - 32) * 8;
    #pragma unroll
    for (int jj = 0; jj < 4; ++jj) {
      int idx = tid + jj*256;
      int el = idx >> 7, hh = idx & 127;
      int e = e0 + el;
      int kc = e >> 6, ks = (e >> 5) & 1, lg = (e >> 3) & 3, j = e & 7;
      int nt = hh >> 4, lr = hh & 15;
      int dst = (((kc*2 + ks)*8 + nt)*64 + lg*16 + lr)*8 + j;
      WTpack[dst] = f2h(W_enc[e*128 + hh]);
    }
  } else {
    if (tid < 128) {
      const int h = tid;
      for (int k = 0; k < 31; ++k) {
        float a = 0.f;
        #pragma unroll
        for (int c = 0; c < 32; ++c) a = fmaf(conv_w[c*31 + k], W_att[c*128 + h], a);
        MTg[h*32 + k] = f2h(a);
      }
      MTg[h*32 + 31] = 0;
    }
  }
}

// ---------------- energy v3: LINEAR 1KB A-loads -> wave-private LDS tile -> MFMA ----------------
// Block = 512 threads (8 waves x 16 rows = 128 t). B staged per E-half (64KB). Per half, each
// wave streams its contiguous 32KB row-slab half (16 x 1KB coalesced loads), cvt f16, ds_write
// into XOR-swizzled [16][256] f16 tile, reads fragments back (2-way bank alias = free).
// Element values / f2h / clamp / MFMA order identical to r11 -> absmax must stay 4.882812e-4.
__global__ __launch_bounds__(512, 2) void energy_kernel(
    const float* __restrict__ enc, const float* __restrict__ prev,
    const unsigned short* __restrict__ WTpack, const unsigned short* __restrict__ MTg,
    const float* __restrict__ decb, const float* __restrict__ W_out,
    float* __restrict__ energy)
{
  extern __shared__ __align__(16) char smem[];
  char* sB = smem;                                          // 65536 B (B half)
  char* sA = smem + 65536;                                  // 65536 B (8 waves x 8KB)
  unsigned short* sMT = (unsigned short*)(smem + 131072);   // 8192 B
  float* sPrev = (float*)(smem + 139264);                   // 640 B
  float* sDecb = (float*)(smem + 139904);                   // 512 B
  float* sWout = (float*)(smem + 140416);                   // 512 B

  const int b  = blockIdx.y;
  const int t0 = blockIdx.x * 128;
  const int tid = threadIdx.x;
  const int wave = tid >> 6, lane = tid & 63;
  const int lr = lane & 15, lg = lane >> 4;

  const float* encB = enc + (size_t)b * (2000u*512u);

  // ---- prologue: B0 (L2) + A0 (HBM linear) + small stages ----
  uint4 rb[8];
  {
    const uint4* wsrc = (const uint4*)WTpack;   // half 0 = first 64KB
    #pragma unroll
    for (int i = 0; i < 8; ++i) rb[i] = wsrc[tid + i*512];
  }
  float4 ra[16];
  #pragma unroll
  for (int i = 0; i < 16; ++i) {
    int row = t0 + wave*16 + i; if (row > 1999) row = 1999;
    ra[i] = *reinterpret_cast<const float4*>(encB + (size_t)row*512 + lane*4);
  }
  ((uint4*)sMT)[tid] = ((const uint4*)MTg)[tid & 511];
  if (tid < 160) {
    int tt = t0 + tid - 15;
    sPrev[tid] = (tt >= 0 && tt < 2000) ? prev[b*2000 + tt] : 0.f;
  }
  if (tid < 128) { sDecb[tid] = decb[b*128 + tid]; sWout[tid] = W_out[tid]; }
  {
    uint4* wdst = (uint4*)sB;
    #pragma unroll
    for (int i = 0; i < 8; ++i) wdst[tid + i*512] = rb[i];
  }
  char* aw = sA + wave*8192;
  #pragma unroll
  for (int i = 0; i < 16; ++i) {
    uint2 wv;
    wv.x = ((unsigned)f2h(ra[i].y) << 16) | f2h(ra[i].x);
    wv.y = ((unsigned)f2h(ra[i].w) << 16) | f2h(ra[i].z);
    *reinterpret_cast<uint2*>(aw + i*512 + ((lane*8) ^ ((i & 7) << 4))) = wv;
  }
  __syncthreads();

  f32x4 acc[8];
  #pragma unroll
  for (int i = 0; i < 8; ++i) acc[i] = (f32x4){0,0,0,0};

  const char* ar = sA + wave*8192 + lr*512;
  const int sw = (lr & 7) << 4;

  // issue half-1 A (HBM linear) + B1 (L2) prefetch; stay in flight under half-0 compute
  float4 na[16];
  #pragma unroll
  for (int i = 0; i < 16; ++i) {
    int row = t0 + wave*16 + i; if (row > 1999) row = 1999;
    na[i] = *reinterpret_cast<const float4*>(encB + (size_t)row*512 + 256 + lane*4);
  }
  uint4 nb[8];
  {
    const uint4* wsrc = (const uint4*)WTpack + 4096;  // half 1
    #pragma unroll
    for (int i = 0; i < 8; ++i) nb[i] = wsrc[tid + i*512];
  }

  // ---- half 0 compute: kc 0..3 ----
  #pragma unroll
  for (int kc = 0; kc < 4; ++kc) {
    f16x8 a0 = *reinterpret_cast<const f16x8*>(ar + ((kc*128 + 0  + lg*16) ^ sw));
    f16x8 a1 = *reinterpret_cast<const f16x8*>(ar + ((kc*128 + 64 + lg*16) ^ sw));
    #pragma unroll
    for (int nt = 0; nt < 8; ++nt) {
      uint4 rv = *reinterpret_cast<const uint4*>(sB + ((kc*2 + 0)*8 + nt)*1024 + lane*16);
      acc[nt] = __builtin_amdgcn_mfma_f32_16x16x32_f16(a0, u4_to_f16x8(rv), acc[nt], 0, 0, 0);
    }
    #pragma unroll
    for (int nt = 0; nt < 8; ++nt) {
      uint4 rv = *reinterpret_cast<const uint4*>(sB + ((kc*2 + 1)*8 + nt)*1024 + lane*16);
      acc[nt] = __builtin_amdgcn_mfma_f32_16x16x32_f16(a1, u4_to_f16x8(rv), acc[nt], 0, 0, 0);
    }
  }

  // WAR fence on wave-private A tile, then write half-1 A
  asm volatile("s_waitcnt lgkmcnt(0)" ::: "memory");
  __builtin_amdgcn_sched_barrier(0);
  #pragma unroll
  for (int i = 0; i < 16; ++i) {
    uint2 wv;
    wv.x = ((unsigned)f2h(na[i].y) << 16) | f2h(na[i].x);
    wv.y = ((unsigned)f2h(na[i].w) << 16) | f2h(na[i].z);
    *reinterpret_cast<uint2*>(aw + i*512 + ((lane*8) ^ ((i & 7) << 4))) = wv;
  }
  __syncthreads();   // all waves done reading B0
  {
    uint4* wdst = (uint4*)sB;
    #pragma unroll
    for (int i = 0; i < 8; ++i) wdst[tid + i*512] = nb[i];
  }
  __syncthreads();   // B1 visible

  // ---- half 1 compute: kc 4..7 ----
  #pragma unroll
  for (int kcl = 0; kcl < 4; ++kcl) {
    f16x8 a0 = *reinterpret_cast<const f16x8*>(ar + ((kcl*128 + 0  + lg*16) ^ sw));
    f16x8 a1 = *reinterpret_cast<const f16x8*>(ar + ((kcl*128 + 64 + lg*16) ^ sw));
    #pragma unroll
    for (int nt = 0; nt < 8; ++nt) {
      uint4 rv = *reinterpret_cast<const uint4*>(sB + ((kcl*2 + 0)*8 + nt)*1024 + lane*16);
      acc[nt] = __builtin_amdgcn_mfma_f32_16x16x32_f16(a0, u4_to_f16x8(rv), acc[nt], 0, 0, 0);
    }
    #pragma unroll
    for (int nt = 0; nt < 8; ++nt) {
      uint4 rv = *reinterpret_cast<const uint4*>(sB + ((kcl*2 + 1)*8 + nt)*1024 + lane*16);
      acc[nt] = __builtin_amdgcn_mfma_f32_16x16x32_f16(a1, u4_to_f16x8(rv), acc[nt], 0, 0, 0);
    }
  }

  // conv as MFMA (identical math to r11)
  {
    f16x8 a2;
    const int pb0 = wave*16 + lr + lg*8;
    #pragma unroll
    for (int j = 0; j < 8; ++j)
      a2[j] = __builtin_bit_cast(_Float16, f2h(sPrev[pb0 + j]));
    const char* mlds = (const char*)sMT + lr*64 + lg*16;
    #pragma unroll
    for (int nt = 0; nt < 8; ++nt) {
      uint4 mv = *reinterpret_cast<const uint4*>(mlds + nt*1024);
      acc[nt] = __builtin_amdgcn_mfma_f32_16x16x32_f16(a2, u4_to_f16x8(mv), acc[nt], 0, 0, 0);
    }
  }

  // epilogue: + dec, tanh, dot W_out, reduce over h (lr)
  {
    float es0 = 0.f, es1 = 0.f, es2 = 0.f, es3 = 0.f;
    #pragma unroll
    for (int nt = 0; nt < 8; ++nt) {
      float dh = sDecb[nt*16 + lr];
      float wo = sWout[nt*16 + lr];
      es0 += fast_tanh(acc[nt][0] + dh) * wo;
      es1 += fast_tanh(acc[nt][1] + dh) * wo;
      es2 += fast_tanh(acc[nt][2] + dh) * wo;
      es3 += fast_tanh(acc[nt][3] + dh) * wo;
    }
    #pragma unroll
    for (int off = 1; off < 16; off <<= 1) {
      es0 += __shfl_xor(es0, off, 64);
      es1 += __shfl_xor(es1, off, 64);
      es2 += __shfl_xor(es2, off, 64);
      es3 += __shfl_xor(es3, off, 64);
    }
    if (lr == 0) {
      const int t = t0 + wave*16 + lg*4;
      float ev[4] = {es0, es1, es2, es3};
      #pragma unroll
      for (int r = 0; r < 4; ++r)
        if (t + r < 2000) energy[b*2000 + t + r] = ev[r];
    }
  }
}

// ---------------- softmax over T per b -> att_w ----------------
__global__ __launch_bounds__(256) void softmax_kernel(
    const float* __restrict__ energy, float* __restrict__ attw)
{
  const int b = blockIdx.x, tid = threadIdx.x;
  __shared__ float red[4];
  __shared__ float red2[4];
  float m = -1e30f;
  for (int i = tid; i < 2000; i += 256) m = fmaxf(m, energy[b*2000 + i]);
  #pragma unroll
  for (int off = 1; off < 64; off <<= 1) m = fmaxf(m, __shfl_xor(m, off, 64));
  if ((tid & 63) == 0) red[tid >> 6] = m;
  __syncthreads();
  m = fmaxf(fmaxf(red[0], red[1]), fmaxf(red[2], red[3]));

  float s = 0.f;
  for (int i = tid; i < 2000; i += 256) {
    float p = __expf(energy[b*2000 + i] - m);
    attw[b*2000 + i] = p;
    s += p;
  }
  #pragma unroll
  for (int off = 1; off < 64; off <<= 1) s += __shfl_xor(s, off, 64);
  if ((tid & 63) == 0) red2[tid >> 6] = s;
  __syncthreads();
  s = red2[0] + red2[1] + red2[2] + red2[3];
  float inv = 1.f / s;
  for (int i = tid; i < 2000; i += 256) attw[b*2000 + i] *= inv;
}

// ---------------- att_c partials: float4 loads, t-parity split (32 partials/b) ----------------
__global__ __launch_bounds__(256) void attc_partial_kernel(
    const float* __restrict__ enc, const float* __restrict__ attw,
    float* __restrict__ part)
{
  const int b = blockIdx.y, ch = blockIdx.x, tid = threadIdx.x;
  const int p = tid >> 7;
  const int e4 = (tid & 127) * 4;
  const int tstart = ch * 125 + p, tend = ch * 125 + 125;
  const float* encB = enc + (size_t)b * (2000u*512u);
  float a0 = 0.f, a1 = 0.f, a2 = 0.f, a3 = 0.f;
  #pragma unroll 2
  for (int t = tstart; t < tend; t += 2) {
    float w = attw[b*2000 + t];
    float4 v = *reinterpret_cast<const float4*>(encB + (size_t)t*512 + e4);
    a0 = fmaf(v.x, w, a0);
    a1 = fmaf(v.y, w, a1);
    a2 = fmaf(v.z, w, a2);
    a3 = fmaf(v.w, w, a3);
  }
  float4 out = {a0, a1, a2, a3};
  *reinterpret_cast<float4*>(part + ((size_t)(b*32 + ch*2 + p))*512 + e4) = out;
}

__global__ __launch_bounds__(128) void attc_reduce_kernel(
    const float* __restrict__ part, float* __restrict__ out)
{
  const int b = blockIdx.x, e4 = threadIdx.x * 4;
  float4 s = {0.f, 0.f, 0.f, 0.f};
  #pragma unroll
  for (int c = 0; c < 32; ++c) {
    float4 v = *reinterpret_cast<const float4*>(part + ((size_t)(b*32 + c))*512 + e4);
    s.x += v.x; s.y += v.y; s.z += v.z; s.w += v.w;
  }
  *reinterpret_cast<float4*>(out + b*512 + e4) = s;
}

// ---------------- launch ----------------
extern "C" void kernel_launch(void* const* d_in, const int* in_sizes, int n_in,
                              void* d_out, int out_size, void* d_ws, size_t ws_size,
                              hipStream_t stream) {
  (void)in_sizes; (void)n_in; (void)out_size; (void)ws_size;
  const float* enc       = (const float*)d_in[0];
  // d_in[1] = text_len: unused by the reference computation
  const float* dec_state = (const float*)d_in[2];
  const float* prev      = (const float*)d_in[3];
  const float* W_enc     = (const float*)d_in[4];
  const float* b_enc     = (const float*)d_in[5];
  const float* W_dec     = (const float*)d_in[6];
  const float* W_att     = (const float*)d_in[7];
  const float* conv_w    = (const float*)d_in[8];
  const float* W_out     = (const float*)d_in[9];
  // d_in[10] = b_out: softmax-invariant, dropped

  char* ws = (char*)d_ws;
  float*          energy = (float*)(ws + 0);               // 524288
  float*          decb   = (float*)(ws + 524288);          // 32768
  unsigned short* MTg    = (unsigned short*)(ws + 557056); // 8192
  unsigned short* WTpack = (unsigned short*)(ws + 565248); // 131072
  float*          part   = (float*)(ws + 696320);          // 4194304

  float* attc = (float*)d_out;             // (64, 512)
  float* attw = (float*)d_out + 64*512;    // (64, 2000)

  const int lds_bytes = 140928;   // 64K B-half + 64K A-tiles + MTg + prev/dec/wout

  prep_kernel        <<<97, 256, 0, stream>>>(dec_state, W_dec, b_enc, conv_w, W_att, W_enc,
                                              decb, MTg, WTpack);
  energy_kernel      <<<dim3(16, 64), 512, lds_bytes, stream>>>(enc, prev, WTpack, MTg, decb, W_out, energy);
  softmax_kernel     <<<64, 256, 0, stream>>>(energy, attw);
  attc_partial_kernel<<<dim3(16, 64), 256, 0, stream>>>(enc, attw, part);
  attc_reduce_kernel <<<64, 128, 0, stream>>>(part, attc);
}

// Round 18
// 205.255 us; speedup vs baseline: 1.3107x; 1.0598x over previous
//
#include <hip/hip_runtime.h>
#include <hip/hip_fp16.h>

typedef _Float16 f16x8 __attribute__((ext_vector_type(8)));
typedef float f32x4 __attribute__((ext_vector_type(4)));

// B=64, T=2000, E=512, D=1024, CC=32, K=31, H=128, PAD=15

__device__ __forceinline__ unsigned short f2h(float f) {
  __half h = __float2half(f);   // v_cvt_f16_f32, RNE
  return __builtin_bit_cast(unsigned short, h);
}

__device__ __forceinline__ f16x8 u4_to_f16x8(uint4 v) {
  return __builtin_bit_cast(f16x8, v);
}

__device__ __forceinline__ f16x8 cvt8(float4 u, float4 v) {
  uint4 w;
  w.x = ((unsigned)f2h(u.y) << 16) | f2h(u.x);
  w.y = ((unsigned)f2h(u.w) << 16) | f2h(u.z);
  w.z = ((unsigned)f2h(v.y) << 16) | f2h(v.x);
  w.w = ((unsigned)f2h(v.w) << 16) | f2h(v.z);
  return u4_to_f16x8(w);
}

__device__ __forceinline__ float fast_tanh(float x) {
  return 1.f - 2.f / (__expf(2.f * x) + 1.f);
}

// async global->LDS, 16B per lane, data never touches VGPRs (vmcnt-counted)
__device__ __forceinline__ void glds16(const float* g, char* l) {
  __builtin_amdgcn_global_load_lds(
      (const __attribute__((address_space(1))) void*)g,
      (__attribute__((address_space(3))) void*)l,
      16, 0, 0);
}

// ---------------- misc prep (r11 verbatim) ----------------
__global__ __launch_bounds__(256) void prep_kernel(
    const float* __restrict__ dec_state, const float* __restrict__ W_dec,
    const float* __restrict__ b_enc, const float* __restrict__ conv_w,
    const float* __restrict__ W_att, const float* __restrict__ W_enc,
    float* __restrict__ decb, unsigned short* __restrict__ MTg,
    unsigned short* __restrict__ WTpack)
{
  const int blk = blockIdx.x, tid = threadIdx.x;
  if (blk < 32) {
    __shared__ float sd[2048];
    const int sub = tid >> 7, h = tid & 127;
    const int b = blk*2 + sub;
    for (int i = h; i < 1024; i += 128) sd[sub*1024 + i] = dec_state[b*1024 + i];
    __syncthreads();
    float acc = b_enc[h];
    #pragma unroll 8
    for (int d = 0; d < 1024; ++d) acc = fmaf(sd[sub*1024 + d], W_dec[d*128 + h], acc);
    decb[b*128 + h] = acc;
  } else if (blk < 96) {
    const int e0 = (blk - 32) * 8;
    #pragma unroll
    for (int jj = 0; jj < 4; ++jj) {
      int idx = tid + jj*256;
      int el = idx >> 7, hh = idx & 127;
      int e = e0 + el;
      int kc = e >> 6, ks = (e >> 5) & 1, lg = (e >> 3) & 3, j = e & 7;
      int nt = hh >> 4, lr = hh & 15;
      int dst = (((kc*2 + ks)*8 + nt)*64 + lg*16 + lr)*8 + j;
      WTpack[dst] = f2h(W_enc[e*128 + hh]);
    }
  } else {
    if (tid < 128) {
      const int h = tid;
      for (int k = 0; k < 31; ++k) {
        float a = 0.f;
        #pragma unroll
        for (int c = 0; c < 32; ++c) a = fmaf(conv_w[c*31 + k], W_att[c*128 + h], a);
        MTg[h*32 + k] = f2h(a);
      }
      MTg[h*32 + 31] = 0;
    }
  }
}

// ---------------- energy v4: A via global_load_lds (VGPR-free in-flight depth) ----------------
// 512 thr / 8 waves, wave owns 16 rows. A fp32 staged to wave-private LDS (2-slot ring, 4 glds/kc,
// source XOR-swizzled per 16B unit so read-back is <=2-way). Counted vmcnt(4) per kc (never drain).
// B per-half in LDS with RAW s_barrier (no vmcnt drain). Values/order bit-identical to r11.
__global__ __launch_bounds__(512, 2) void energy_kernel(
    const float* __restrict__ enc, const float* __restrict__ prev,
    const unsigned short* __restrict__ WTpack, const unsigned short* __restrict__ MTg,
    const float* __restrict__ decb, const float* __restrict__ W_out,
    float* __restrict__ energy)
{
  extern __shared__ __align__(16) char smem[];
  char* sB = smem;                                          // 65536 (B half: 16 frag x 4KB... 8KB/fs pair)
  char* sA = smem + 65536;                                  // 65536 (2 slots x 128 rows x 256B)
  unsigned short* sMT = (unsigned short*)(smem + 131072);   // 8192
  float* sPrev = (float*)(smem + 139264);                   // 640
  float* sDecb = (float*)(smem + 139904);                   // 512
  float* sWout = (float*)(smem + 140416);                   // 512

  const int b  = blockIdx.y;
  const int t0 = blockIdx.x * 128;
  const int tid = threadIdx.x;
  const int wave = tid >> 6, lane = tid & 63;
  const int lr = lane & 15, lg = lane >> 4;

  const float* encB = enc + (size_t)b * (2000u*512u);

  // per-lane glds source geometry: instruction q covers rows R..R+3 (R = wave*16+q*4)
  // lane: r = R + (lane>>4), u = lane&15 ; src unit = u ^ (r&7)  (inverse of read swizzle)
  int srows[4]; const float* gsrc[4];
  #pragma unroll
  for (int q = 0; q < 4; ++q) {
    int r = wave*16 + q*4 + (lane >> 4);
    int rg = t0 + r; if (rg > 1999) rg = 1999;      // clamp; rows>=2000 never written out
    srows[q] = r;
    gsrc[q] = encB + (size_t)rg*512 + (((lane & 15) ^ (r & 7)) << 2);
  }

  // ---- prologue reg loads (VMEM, L2-hot) ----
  uint4 rb[8], nb[8];
  {
    const uint4* wsrc = (const uint4*)WTpack;
    #pragma unroll
    for (int i = 0; i < 8; ++i) rb[i] = wsrc[tid + i*512];        // B half 0
    #pragma unroll
    for (int i = 0; i < 8; ++i) nb[i] = wsrc[4096 + tid + i*512]; // B half 1
  }
  uint4 mt = ((const uint4*)MTg)[tid & 511];
  float pv = 0.f;
  if (tid < 160) {
    int tt = t0 + tid - 15;
    pv = (tt >= 0 && tt < 2000) ? prev[b*2000 + tt] : 0.f;
  }
  float dv = 0.f, wv = 0.f;
  if (tid < 128) { dv = decb[b*128 + tid]; wv = W_out[tid]; }

  // ---- issue glds for kc=0 (slot0) and kc=1 (slot1): 8 x 1KB per wave in flight ----
  #pragma unroll
  for (int q = 0; q < 4; ++q)
    glds16(gsrc[q] + 0*64, sA + 0*32768 + (wave*16 + q*4)*256);
  #pragma unroll
  for (int q = 0; q < 4; ++q)
    glds16(gsrc[q] + 1*64, sA + 1*32768 + (wave*16 + q*4)*256);

  // ---- LDS stores (compiler waits vmcnt on rb/mt only; glds stay outstanding) ----
  {
    uint4* wdst = (uint4*)sB;
    #pragma unroll
    for (int i = 0; i < 8; ++i) wdst[tid + i*512] = rb[i];
  }
  ((uint4*)sMT)[tid & 511] = mt;    // tid 0..511 all write (512 entries, dup-free: tid&511==tid)
  if (tid < 160) sPrev[tid] = pv;
  if (tid < 128) { sDecb[tid] = dv; sWout[tid] = wv; }
  asm volatile("s_waitcnt lgkmcnt(0)" ::: "memory");
  __builtin_amdgcn_sched_barrier(0);
  __builtin_amdgcn_s_barrier();     // RAW barrier: glds remain in flight

  f32x4 acc[8];
  #pragma unroll
  for (int i = 0; i < 8; ++i) acc[i] = (f32x4){0,0,0,0};

  const char* arow = sA + (wave*16 + lr)*256;
  const int sw = lr & 7;

  #pragma unroll
  for (int kc = 0; kc < 8; ++kc) {
    const int slot = kc & 1;
    // A(kc) landed when <=4 glds outstanding (only kc+1's remain)
    if (kc < 7) { asm volatile("s_waitcnt vmcnt(4)" ::: "memory"); }
    else       { asm volatile("s_waitcnt vmcnt(0)" ::: "memory"); }
    __builtin_amdgcn_sched_barrier(0);

    const char* ap = arow + slot*32768;
    float4 a00 = *reinterpret_cast<const float4*>(ap + (((lg*2 + 0) ^ sw) << 4));
    float4 a01 = *reinterpret_cast<const float4*>(ap + (((lg*2 + 1) ^ sw) << 4));
    float4 a10 = *reinterpret_cast<const float4*>(ap + (((8 + lg*2 + 0) ^ sw) << 4));
    float4 a11 = *reinterpret_cast<const float4*>(ap + (((8 + lg*2 + 1) ^ sw) << 4));
    asm volatile("s_waitcnt lgkmcnt(0)" ::: "memory");   // slot reads done -> safe to refill
    __builtin_amdgcn_sched_barrier(0);
    if (kc < 6) {
      #pragma unroll
      for (int q = 0; q < 4; ++q)
        glds16(gsrc[q] + (kc+2)*64, sA + slot*32768 + (wave*16 + q*4)*256);
    }

    f16x8 A0 = cvt8(a00, a01);   // ks=0, k = kc*64 + lg*8 + j     (bit-identical to r11)
    f16x8 A1 = cvt8(a10, a11);   // ks=1, k = kc*64 + 32 + lg*8 + j
    const int fs0 = (kc & 3)*2, fs1 = (kc & 3)*2 + 1;
    #pragma unroll
    for (int nt = 0; nt < 8; ++nt) {
      uint4 rv = *reinterpret_cast<const uint4*>(sB + ((fs0*8 + nt)*1024) + lane*16);
      acc[nt] = __builtin_amdgcn_mfma_f32_16x16x32_f16(A0, u4_to_f16x8(rv), acc[nt], 0, 0, 0);
    }
    #pragma unroll
    for (int nt = 0; nt < 8; ++nt) {
      uint4 rv = *reinterpret_cast<const uint4*>(sB + ((fs1*8 + nt)*1024) + lane*16);
      acc[nt] = __builtin_amdgcn_mfma_f32_16x16x32_f16(A1, u4_to_f16x8(rv), acc[nt], 0, 0, 0);
    }

    if (kc == 3) {
      // swap B half: raw barriers, glds (kc=4,5 slots) stay in flight
      asm volatile("s_waitcnt lgkmcnt(0)" ::: "memory");
      __builtin_amdgcn_sched_barrier(0);
      __builtin_amdgcn_s_barrier();
      {
        uint4* wdst = (uint4*)sB;
        #pragma unroll
        for (int i = 0; i < 8; ++i) wdst[tid + i*512] = nb[i];
      }
      asm volatile("s_waitcnt lgkmcnt(0)" ::: "memory");
      __builtin_amdgcn_sched_barrier(0);
      __builtin_amdgcn_s_barrier();
    }
  }

  // conv as MFMA (identical math to r11)
  {
    f16x8 a2;
    const int pb0 = wave*16 + lr + lg*8;
    #pragma unroll
    for (int j = 0; j < 8; ++j)
      a2[j] = __builtin_bit_cast(_Float16, f2h(sPrev[pb0 + j]));
    const char* mlds = (const char*)sMT + lr*64 + lg*16;
    #pragma unroll
    for (int nt = 0; nt < 8; ++nt) {
      uint4 mv = *reinterpret_cast<const uint4*>(mlds + nt*1024);
      acc[nt] = __builtin_amdgcn_mfma_f32_16x16x32_f16(a2, u4_to_f16x8(mv), acc[nt], 0, 0, 0);
    }
  }

  // epilogue: + dec, tanh, dot W_out, reduce over h (lr)
  {
    float es0 = 0.f, es1 = 0.f, es2 = 0.f, es3 = 0.f;
    #pragma unroll
    for (int nt = 0; nt < 8; ++nt) {
      float dh = sDecb[nt*16 + lr];
      float wo = sWout[nt*16 + lr];
      es0 += fast_tanh(acc[nt][0] + dh) * wo;
      es1 += fast_tanh(acc[nt][1] + dh) * wo;
      es2 += fast_tanh(acc[nt][2] + dh) * wo;
      es3 += fast_tanh(acc[nt][3] + dh) * wo;
    }
    #pragma unroll
    for (int off = 1; off < 16; off <<= 1) {
      es0 += __shfl_xor(es0, off, 64);
      es1 += __shfl_xor(es1, off, 64);
      es2 += __shfl_xor(es2, off, 64);
      es3 += __shfl_xor(es3, off, 64);
    }
    if (lr == 0) {
      const int t = t0 + wave*16 + lg*4;
      float ev[4] = {es0, es1, es2, es3};
      #pragma unroll
      for (int r = 0; r < 4; ++r)
        if (t + r < 2000) energy[b*2000 + t + r] = ev[r];
    }
  }
}

// ---------------- softmax over T per b -> att_w (r11 verbatim) ----------------
__global__ __launch_bounds__(256) void softmax_kernel(
    const float* __restrict__ energy, float* __restrict__ attw)
{
  const int b = blockIdx.x, tid = threadIdx.x;
  __shared__ float red[4];
  __shared__ float red2[4];
  float m = -1e30f;
  for (int i = tid; i < 2000; i += 256) m = fmaxf(m, energy[b*2000 + i]);
  #pragma unroll
  for (int off = 1; off < 64; off <<= 1) m = fmaxf(m, __shfl_xor(m, off, 64));
  if ((tid & 63) == 0) red[tid >> 6] = m;
  __syncthreads();
  m = fmaxf(fmaxf(red[0], red[1]), fmaxf(red[2], red[3]));

  float s = 0.f;
  for (int i = tid; i < 2000; i += 256) {
    float p = __expf(energy[b*2000 + i] - m);
    attw[b*2000 + i] = p;
    s += p;
  }
  #pragma unroll
  for (int off = 1; off < 64; off <<= 1) s += __shfl_xor(s, off, 64);
  if ((tid & 63) == 0) red2[tid >> 6] = s;
  __syncthreads();
  s = red2[0] + red2[1] + red2[2] + red2[3];
  float inv = 1.f / s;
  for (int i = tid; i < 2000; i += 256) attw[b*2000 + i] *= inv;
}

// ---------------- att_c partials (r11 verbatim) ----------------
__global__ __launch_bounds__(256) void attc_partial_kernel(
    const float* __restrict__ enc, const float* __restrict__ attw,
    float* __restrict__ part)
{
  const int b = blockIdx.y, ch = blockIdx.x, tid = threadIdx.x;
  const int p = tid >> 7;
  const int e4 = (tid & 127) * 4;
  const int tstart = ch * 125 + p, tend = ch * 125 + 125;
  const float* encB = enc + (size_t)b * (2000u*512u);
  float a0 = 0.f, a1 = 0.f, a2 = 0.f, a3 = 0.f;
  #pragma unroll 2
  for (int t = tstart; t < tend; t += 2) {
    float w = attw[b*2000 + t];
    float4 v = *reinterpret_cast<const float4*>(encB + (size_t)t*512 + e4);
    a0 = fmaf(v.x, w, a0);
    a1 = fmaf(v.y, w, a1);
    a2 = fmaf(v.z, w, a2);
    a3 = fmaf(v.w, w, a3);
  }
  float4 out = {a0, a1, a2, a3};
  *reinterpret_cast<float4*>(part + ((size_t)(b*32 + ch*2 + p))*512 + e4) = out;
}

__global__ __launch_bounds__(128) void attc_reduce_kernel(
    const float* __restrict__ part, float* __restrict__ out)
{
  const int b = blockIdx.x, e4 = threadIdx.x * 4;
  float4 s = {0.f, 0.f, 0.f, 0.f};
  #pragma unroll
  for (int c = 0; c < 32; ++c) {
    float4 v = *reinterpret_cast<const float4*>(part + ((size_t)(b*32 + c))*512 + e4);
    s.x += v.x; s.y += v.y; s.z += v.z; s.w += v.w;
  }
  *reinterpret_cast<float4*>(out + b*512 + e4) = s;
}

// ---------------- launch ----------------
extern "C" void kernel_launch(void* const* d_in, const int* in_sizes, int n_in,
                              void* d_out, int out_size, void* d_ws, size_t ws_size,
                              hipStream_t stream) {
  (void)in_sizes; (void)n_in; (void)out_size; (void)ws_size;
  const float* enc       = (const float*)d_in[0];
  // d_in[1] = text_len: unused by the reference computation
  const float* dec_state = (const float*)d_in[2];
  const float* prev      = (const float*)d_in[3];
  const float* W_enc     = (const float*)d_in[4];
  const float* b_enc     = (const float*)d_in[5];
  const float* W_dec     = (const float*)d_in[6];
  const float* W_att     = (const float*)d_in[7];
  const float* conv_w    = (const float*)d_in[8];
  const float* W_out     = (const float*)d_in[9];
  // d_in[10] = b_out: softmax-invariant, dropped

  char* ws = (char*)d_ws;
  float*          energy = (float*)(ws + 0);               // 524288
  float*          decb   = (float*)(ws + 524288);          // 32768
  unsigned short* MTg    = (unsigned short*)(ws + 557056); // 8192
  unsigned short* WTpack = (unsigned short*)(ws + 565248); // 131072
  float*          part   = (float*)(ws + 696320);          // 4194304

  float* attc = (float*)d_out;             // (64, 512)
  float* attw = (float*)d_out + 64*512;    // (64, 2000)

  const int lds_bytes = 140928;   // 64K B-half + 64K A ring + MT/prev/dec/wout

  prep_kernel        <<<97, 256, 0, stream>>>(dec_state, W_dec, b_enc, conv_w, W_att, W_enc,
                                              decb, MTg, WTpack);
  energy_kernel      <<<dim3(16, 64), 512, lds_bytes, stream>>>(enc, prev, WTpack, MTg, decb, W_out, energy);
  softmax_kernel     <<<64, 256, 0, stream>>>(energy, attw);
  attc_partial_kernel<<<dim3(16, 64), 256, 0, stream>>>(enc, attw, part);
  attc_reduce_kernel <<<64, 128, 0, stream>>>(part, attc);
}

// Round 19
// 155.640 us; speedup vs baseline: 1.7286x; 1.3188x over previous
//
#include <hip/hip_runtime.h>
#include <hip/hip_fp16.h>

typedef _Float16 f16x8 __attribute__((ext_vector_type(8)));
typedef float f32x4 __attribute__((ext_vector_type(4)));

// B=64, T=2000, E=512, D=1024, CC=32, K=31, H=128, PAD=15

__device__ __forceinline__ unsigned short f2h(float f) {
  __half h = __float2half(f);   // v_cvt_f16_f32, RNE
  return __builtin_bit_cast(unsigned short, h);
}

__device__ __forceinline__ f16x8 u4_to_f16x8(uint4 v) {
  return __builtin_bit_cast(f16x8, v);
}

__device__ __forceinline__ float fast_tanh(float x) {
  return 1.f - 2.f / (__expf(2.f * x) + 1.f);
}

// ---------------- misc prep (r11 verbatim) ----------------
__global__ __launch_bounds__(256) void prep_kernel(
    const float* __restrict__ dec_state, const float* __restrict__ W_dec,
    const float* __restrict__ b_enc, const float* __restrict__ conv_w,
    const float* __restrict__ W_att, const float* __restrict__ W_enc,
    float* __restrict__ decb, unsigned short* __restrict__ MTg,
    unsigned short* __restrict__ WTpack)
{
  const int blk = blockIdx.x, tid = threadIdx.x;
  if (blk < 32) {
    __shared__ float sd[2048];
    const int sub = tid >> 7, h = tid & 127;
    const int b = blk*2 + sub;
    for (int i = h; i < 1024; i += 128) sd[sub*1024 + i] = dec_state[b*1024 + i];
    __syncthreads();
    float acc = b_enc[h];
    #pragma unroll 8
    for (int d = 0; d < 1024; ++d) acc = fmaf(sd[sub*1024 + d], W_dec[d*128 + h], acc);
    decb[b*128 + h] = acc;
  } else if (blk < 96) {
    const int e0 = (blk - 32) * 8;
    #pragma unroll
    for (int jj = 0; jj < 4; ++jj) {
      int idx = tid + jj*256;
      int el = idx >> 7, hh = idx & 127;
      int e = e0 + el;
      int kc = e >> 6, ks = (e >> 5) & 1, lg = (e >> 3) & 3, j = e & 7;
      int nt = hh >> 4, lr = hh & 15;
      int dst = (((kc*2 + ks)*8 + nt)*64 + lg*16 + lr)*8 + j;
      WTpack[dst] = f2h(W_enc[e*128 + hh]);
    }
  } else {
    if (tid < 128) {
      const int h = tid;
      for (int k = 0; k < 31; ++k) {
        float a = 0.f;
        #pragma unroll
        for (int c = 0; c < 32; ++c) a = fmaf(conv_w[c*31 + k], W_att[c*128 + h], a);
        MTg[h*32 + k] = f2h(a);
      }
      MTg[h*32 + 31] = 0;
    }
  }
}

// ---------------- energy v5: row-linear A staging (1KB/instr) + LDS-resident B ----------------
// 512 thr / 8 waves / 128 rows. Wave stages its 16 rows: one FULL 1KB half-row per float4-burst
// instruction (DRAM row-friendly; attc-style). A tile [128][512B] f16 in LDS, unit^row swizzle
// (2-way = free). B half 64KB swapped at kc=4 (raw-barrier protocol). A1+B1 bursts issued before
// half-0 compute, PINNED with sched_barrier(0) against hipcc load-sinking (r10/r17 failure mode).
// Values / f2h / clamp / MFMA order bit-identical to r11 -> absmax must stay 4.882812e-4.
__global__ __launch_bounds__(512, 2) void energy_kernel(
    const float* __restrict__ enc, const float* __restrict__ prev,
    const unsigned short* __restrict__ WTpack, const unsigned short* __restrict__ MTg,
    const float* __restrict__ decb, const float* __restrict__ W_out,
    float* __restrict__ energy)
{
  extern __shared__ __align__(16) char smem[];
  char* sB = smem;                                          // 65536 (B half)
  char* sA = smem + 65536;                                  // 65536 ([128 rows][512B] f16)
  unsigned short* sMT = (unsigned short*)(smem + 131072);   // 8192
  float* sPrev = (float*)(smem + 139264);                   // 640
  float* sDecb = (float*)(smem + 139904);                   // 512
  float* sWout = (float*)(smem + 140416);                   // 512

  const int b  = blockIdx.y;
  const int t0 = blockIdx.x * 128;
  const int tid = threadIdx.x;
  const int wave = tid >> 6, lane = tid & 63;
  const int lr = lane & 15, lg = lane >> 4;

  const float* encB = enc + (size_t)b * (2000u*512u);

  // this wave's 16 source rows (clamped)
  const float* rowsrc[16];
  #pragma unroll
  for (int i = 0; i < 16; ++i) {
    int rg = t0 + wave*16 + i; if (rg > 1999) rg = 1999;
    rowsrc[i] = encB + (size_t)rg*512 + lane*4;
  }

  // ---- L2-fast loads first (older in VMEM queue -> their waits don't drain A bursts) ----
  const uint4* wsrc = (const uint4*)WTpack;
  uint4 rb[8];
  #pragma unroll
  for (int i = 0; i < 8; ++i) rb[i] = wsrc[tid + i*512];
  uint4 mt = ((const uint4*)MTg)[tid];
  float pv = 0.f;
  if (tid < 160) {
    int tt = t0 + tid - 15;
    pv = (tt >= 0 && tt < 2000) ? prev[b*2000 + tt] : 0.f;
  }
  float dv = 0.f, wv = 0.f;
  if (tid < 128) { dv = decb[b*128 + tid]; wv = W_out[tid]; }

  // ---- A0 burst: 16 x (full 1KB half-row per wave-instruction), row-linear ----
  float4 a0r[16];
  #pragma unroll
  for (int i = 0; i < 16; ++i) a0r[i] = *reinterpret_cast<const float4*>(rowsrc[i]);

  // ---- stage B0 + consts ----
  {
    uint4* wd = (uint4*)sB;
    #pragma unroll
    for (int i = 0; i < 8; ++i) wd[tid + i*512] = rb[i];
  }
  ((uint4*)sMT)[tid] = mt;
  if (tid < 160) sPrev[tid] = pv;
  if (tid < 128) { sDecb[tid] = dv; sWout[tid] = wv; }

  // ---- stage A0 (cvt f32->f16, unit^row swizzle) ----
  #pragma unroll
  for (int i = 0; i < 16; ++i) {
    int row = wave*16 + i;
    uint2 w2;
    w2.x = ((unsigned)f2h(a0r[i].y) << 16) | f2h(a0r[i].x);
    w2.y = ((unsigned)f2h(a0r[i].w) << 16) | f2h(a0r[i].z);
    *reinterpret_cast<uint2*>(sA + row*512 + (((lane >> 1) ^ (row & 15)) << 4) + (lane & 1)*8) = w2;
  }
  asm volatile("s_waitcnt lgkmcnt(0)" ::: "memory");
  __builtin_amdgcn_sched_barrier(0);
  __builtin_amdgcn_s_barrier();

  // ---- issue A1 burst + B1 loads NOW; pin so they can't sink into their uses ----
  float4 a1r[16];
  #pragma unroll
  for (int i = 0; i < 16; ++i) a1r[i] = *reinterpret_cast<const float4*>(rowsrc[i] + 256);
  uint4 nb[8];
  #pragma unroll
  for (int i = 0; i < 8; ++i) nb[i] = wsrc[4096 + tid + i*512];
  __builtin_amdgcn_sched_barrier(0);

  f32x4 acc[8];
  #pragma unroll
  for (int i = 0; i < 8; ++i) acc[i] = (f32x4){0,0,0,0};

  const char* ar = sA + (wave*16 + lr)*512;

  // ---- half 0: kc 0..3 (all operands lgkm-domain; a1r/nb stay in VMEM flight) ----
  #pragma unroll
  for (int kc = 0; kc < 4; ++kc) {
    f16x8 A0 = *reinterpret_cast<const f16x8*>(ar + (((kc*8 + 0 + lg) ^ lr) << 4));
    f16x8 A1 = *reinterpret_cast<const f16x8*>(ar + (((kc*8 + 4 + lg) ^ lr) << 4));
    #pragma unroll
    for (int nt = 0; nt < 8; ++nt) {
      uint4 rv = *reinterpret_cast<const uint4*>(sB + ((kc*2 + 0)*8 + nt)*1024 + lane*16);
      acc[nt] = __builtin_amdgcn_mfma_f32_16x16x32_f16(A0, u4_to_f16x8(rv), acc[nt], 0, 0, 0);
    }
    #pragma unroll
    for (int nt = 0; nt < 8; ++nt) {
      uint4 rv = *reinterpret_cast<const uint4*>(sB + ((kc*2 + 1)*8 + nt)*1024 + lane*16);
      acc[nt] = __builtin_amdgcn_mfma_f32_16x16x32_f16(A1, u4_to_f16x8(rv), acc[nt], 0, 0, 0);
    }
  }

  // ---- swap: A (wave-private, no barrier) then B (raw-barrier protocol) ----
  asm volatile("s_waitcnt lgkmcnt(0)" ::: "memory");   // my A/B half-0 reads retired
  __builtin_amdgcn_sched_barrier(0);
  #pragma unroll
  for (int i = 0; i < 16; ++i) {
    int row = wave*16 + i;
    uint2 w2;
    w2.x = ((unsigned)f2h(a1r[i].y) << 16) | f2h(a1r[i].x);
    w2.y = ((unsigned)f2h(a1r[i].w) << 16) | f2h(a1r[i].z);
    *reinterpret_cast<uint2*>(sA + row*512 + (((lane >> 1) ^ (row & 15)) << 4) + (lane & 1)*8) = w2;
  }
  __builtin_amdgcn_s_barrier();     // all waves done reading B0
  {
    uint4* wd = (uint4*)sB;
    #pragma unroll
    for (int i = 0; i < 8; ++i) wd[tid + i*512] = nb[i];
  }
  asm volatile("s_waitcnt lgkmcnt(0)" ::: "memory");
  __builtin_amdgcn_sched_barrier(0);
  __builtin_amdgcn_s_barrier();     // B1 visible

  // ---- half 1: kc 4..7 ----
  #pragma unroll
  for (int kcl = 0; kcl < 4; ++kcl) {
    f16x8 A0 = *reinterpret_cast<const f16x8*>(ar + (((kcl*8 + 0 + lg) ^ lr) << 4));
    f16x8 A1 = *reinterpret_cast<const f16x8*>(ar + (((kcl*8 + 4 + lg) ^ lr) << 4));
    #pragma unroll
    for (int nt = 0; nt < 8; ++nt) {
      uint4 rv = *reinterpret_cast<const uint4*>(sB + ((kcl*2 + 0)*8 + nt)*1024 + lane*16);
      acc[nt] = __builtin_amdgcn_mfma_f32_16x16x32_f16(A0, u4_to_f16x8(rv), acc[nt], 0, 0, 0);
    }
    #pragma unroll
    for (int nt = 0; nt < 8; ++nt) {
      uint4 rv = *reinterpret_cast<const uint4*>(sB + ((kcl*2 + 1)*8 + nt)*1024 + lane*16);
      acc[nt] = __builtin_amdgcn_mfma_f32_16x16x32_f16(A1, u4_to_f16x8(rv), acc[nt], 0, 0, 0);
    }
  }

  // ---- conv as MFMA (identical math to r11) ----
  {
    f16x8 a2;
    const int pb0 = wave*16 + lr + lg*8;
    #pragma unroll
    for (int j = 0; j < 8; ++j)
      a2[j] = __builtin_bit_cast(_Float16, f2h(sPrev[pb0 + j]));
    const char* mlds = (const char*)sMT + lr*64 + lg*16;
    #pragma unroll
    for (int nt = 0; nt < 8; ++nt) {
      uint4 mv = *reinterpret_cast<const uint4*>(mlds + nt*1024);
      acc[nt] = __builtin_amdgcn_mfma_f32_16x16x32_f16(a2, u4_to_f16x8(mv), acc[nt], 0, 0, 0);
    }
  }

  // ---- epilogue: + dec, tanh, dot W_out, reduce over h ----
  {
    float es0 = 0.f, es1 = 0.f, es2 = 0.f, es3 = 0.f;
    #pragma unroll
    for (int nt = 0; nt < 8; ++nt) {
      float dh = sDecb[nt*16 + lr];
      float wo = sWout[nt*16 + lr];
      es0 += fast_tanh(acc[nt][0] + dh) * wo;
      es1 += fast_tanh(acc[nt][1] + dh) * wo;
      es2 += fast_tanh(acc[nt][2] + dh) * wo;
      es3 += fast_tanh(acc[nt][3] + dh) * wo;
    }
    #pragma unroll
    for (int off = 1; off < 16; off <<= 1) {
      es0 += __shfl_xor(es0, off, 64);
      es1 += __shfl_xor(es1, off, 64);
      es2 += __shfl_xor(es2, off, 64);
      es3 += __shfl_xor(es3, off, 64);
    }
    if (lr == 0) {
      const int t = t0 + wave*16 + lg*4;
      float ev[4] = {es0, es1, es2, es3};
      #pragma unroll
      for (int r = 0; r < 4; ++r)
        if (t + r < 2000) energy[b*2000 + t + r] = ev[r];
    }
  }
}

// ---------------- softmax over T per b -> att_w (r11 verbatim) ----------------
__global__ __launch_bounds__(256) void softmax_kernel(
    const float* __restrict__ energy, float* __restrict__ attw)
{
  const int b = blockIdx.x, tid = threadIdx.x;
  __shared__ float red[4];
  __shared__ float red2[4];
  float m = -1e30f;
  for (int i = tid; i < 2000; i += 256) m = fmaxf(m, energy[b*2000 + i]);
  #pragma unroll
  for (int off = 1; off < 64; off <<= 1) m = fmaxf(m, __shfl_xor(m, off, 64));
  if ((tid & 63) == 0) red[tid >> 6] = m;
  __syncthreads();
  m = fmaxf(fmaxf(red[0], red[1]), fmaxf(red[2], red[3]));

  float s = 0.f;
  for (int i = tid; i < 2000; i += 256) {
    float p = __expf(energy[b*2000 + i] - m);
    attw[b*2000 + i] = p;
    s += p;
  }
  #pragma unroll
  for (int off = 1; off < 64; off <<= 1) s += __shfl_xor(s, off, 64);
  if ((tid & 63) == 0) red2[tid >> 6] = s;
  __syncthreads();
  s = red2[0] + red2[1] + red2[2] + red2[3];
  float inv = 1.f / s;
  for (int i = tid; i < 2000; i += 256) attw[b*2000 + i] *= inv;
}

// ---------------- att_c partials (r11 verbatim) ----------------
__global__ __launch_bounds__(256) void attc_partial_kernel(
    const float* __restrict__ enc, const float* __restrict__ attw,
    float* __restrict__ part)
{
  const int b = blockIdx.y, ch = blockIdx.x, tid = threadIdx.x;
  const int p = tid >> 7;
  const int e4 = (tid & 127) * 4;
  const int tstart = ch * 125 + p, tend = ch * 125 + 125;
  const float* encB = enc + (size_t)b * (2000u*512u);
  float a0 = 0.f, a1 = 0.f, a2 = 0.f, a3 = 0.f;
  #pragma unroll 2
  for (int t = tstart; t < tend; t += 2) {
    float w = attw[b*2000 + t];
    float4 v = *reinterpret_cast<const float4*>(encB + (size_t)t*512 + e4);
    a0 = fmaf(v.x, w, a0);
    a1 = fmaf(v.y, w, a1);
    a2 = fmaf(v.z, w, a2);
    a3 = fmaf(v.w, w, a3);
  }
  float4 out = {a0, a1, a2, a3};
  *reinterpret_cast<float4*>(part + ((size_t)(b*32 + ch*2 + p))*512 + e4) = out;
}

__global__ __launch_bounds__(128) void attc_reduce_kernel(
    const float* __restrict__ part, float* __restrict__ out)
{
  const int b = blockIdx.x, e4 = threadIdx.x * 4;
  float4 s = {0.f, 0.f, 0.f, 0.f};
  #pragma unroll
  for (int c = 0; c < 32; ++c) {
    float4 v = *reinterpret_cast<const float4*>(part + ((size_t)(b*32 + c))*512 + e4);
    s.x += v.x; s.y += v.y; s.z += v.z; s.w += v.w;
  }
  *reinterpret_cast<float4*>(out + b*512 + e4) = s;
}

// ---------------- launch ----------------
extern "C" void kernel_launch(void* const* d_in, const int* in_sizes, int n_in,
                              void* d_out, int out_size, void* d_ws, size_t ws_size,
                              hipStream_t stream) {
  (void)in_sizes; (void)n_in; (void)out_size; (void)ws_size;
  const float* enc       = (const float*)d_in[0];
  // d_in[1] = text_len: unused by the reference computation
  const float* dec_state = (const float*)d_in[2];
  const float* prev      = (const float*)d_in[3];
  const float* W_enc     = (const float*)d_in[4];
  const float* b_enc     = (const float*)d_in[5];
  const float* W_dec     = (const float*)d_in[6];
  const float* W_att     = (const float*)d_in[7];
  const float* conv_w    = (const float*)d_in[8];
  const float* W_out     = (const float*)d_in[9];
  // d_in[10] = b_out: softmax-invariant, dropped

  char* ws = (char*)d_ws;
  float*          energy = (float*)(ws + 0);               // 524288
  float*          decb   = (float*)(ws + 524288);          // 32768
  unsigned short* MTg    = (unsigned short*)(ws + 557056); // 8192
  unsigned short* WTpack = (unsigned short*)(ws + 565248); // 131072
  float*          part   = (float*)(ws + 696320);          // 4194304

  float* attc = (float*)d_out;             // (64, 512)
  float* attw = (float*)d_out + 64*512;    // (64, 2000)

  const int lds_bytes = 140928;   // 64K B-half + 64K A-tile + MT + prev/dec/wout

  prep_kernel        <<<97, 256, 0, stream>>>(dec_state, W_dec, b_enc, conv_w, W_att, W_enc,
                                              decb, MTg, WTpack);
  energy_kernel      <<<dim3(16, 64), 512, lds_bytes, stream>>>(enc, prev, WTpack, MTg, decb, W_out, energy);
  softmax_kernel     <<<64, 256, 0, stream>>>(energy, attw);
  attc_partial_kernel<<<dim3(16, 64), 256, 0, stream>>>(enc, attw, part);
  attc_reduce_kernel <<<64, 128, 0, stream>>>(part, attc);
}